// Round 15
// baseline (321.977 us; speedup 1.0000x reference)
//
#include <hip/hip_runtime.h>
#include <hip/hip_bf16.h>

// Problem constants
#define BB 4
#define NN 4096
#define DD 512
#define HH 8
#define HD 64

typedef __attribute__((ext_vector_type(4))) float f32x4;
typedef __attribute__((ext_vector_type(16))) float f32x16;
typedef __attribute__((ext_vector_type(8))) short short8;
typedef __attribute__((ext_vector_type(4))) unsigned int uint4v;

static __device__ __forceinline__ unsigned short f2bf(float f) {
    unsigned int u = __float_as_uint(f);
    u += 0x7fff + ((u >> 16) & 1);   // RNE
    return (unsigned short)(u >> 16);
}

// ---------------- f32 -> bf16 conversion ----------------
__global__ void convert_bf16(const float* __restrict__ in,
                             unsigned short* __restrict__ out, int n) {
    int i = (blockIdx.x * blockDim.x + threadIdx.x) * 8;
    int stride = gridDim.x * blockDim.x * 8;
    for (; i + 7 < n; i += stride) {
        f32x4 a = *reinterpret_cast<const f32x4*>(in + i);
        f32x4 b = *reinterpret_cast<const f32x4*>(in + i + 4);
        short8 o;
        o[0] = (short)f2bf(a[0]); o[1] = (short)f2bf(a[1]);
        o[2] = (short)f2bf(a[2]); o[3] = (short)f2bf(a[3]);
        o[4] = (short)f2bf(b[0]); o[5] = (short)f2bf(b[1]);
        o[6] = (short)f2bf(b[2]); o[7] = (short)f2bf(b[3]);
        *reinterpret_cast<short8*>(out + i) = o;
    }
}

// Fused convert of the 4 weight matrices (each 512x512)
__global__ void convert_weights(const float* __restrict__ W0, const float* __restrict__ W1,
                                const float* __restrict__ W2, const float* __restrict__ W3,
                                unsigned short* __restrict__ out) {
    int which = blockIdx.x >> 7;            // 128 blocks per matrix
    const float* src = which == 0 ? W0 : which == 1 ? W1 : which == 2 ? W2 : W3;
    unsigned short* dst = out + (size_t)which * DD * DD;
    int i = ((blockIdx.x & 127) * blockDim.x + threadIdx.x) * 8;
    f32x4 a = *reinterpret_cast<const f32x4*>(src + i);
    f32x4 b = *reinterpret_cast<const f32x4*>(src + i + 4);
    short8 o;
    o[0] = (short)f2bf(a[0]); o[1] = (short)f2bf(a[1]);
    o[2] = (short)f2bf(a[2]); o[3] = (short)f2bf(a[3]);
    o[4] = (short)f2bf(b[0]); o[5] = (short)f2bf(b[1]);
    o[6] = (short)f2bf(b[2]); o[7] = (short)f2bf(b[3]);
    *reinterpret_cast<short8*>(dst + i) = o;
}

// ---------------- GEMM tile body ---------------------------------------------
// OUT_MODE: 0 = f32 row-major, 1 = bf16 row-major, 2 = bf16 V-transposed
// (write Vt[(b*8+h)*64 + d][token], token fastest -> 8B/lane stores)
template <int OUT_MODE>
__device__ __forceinline__
void gemm_tile(const unsigned short* __restrict__ A,
               const unsigned short* __restrict__ W,
               const float* __restrict__ bias,
               void* __restrict__ Cout, float scale,
               int brow, int bcol, uint4* ldsA, uint4* ldsB) {
    const int t = threadIdx.x;
    const int lane = t & 63;
    const int w = t >> 6;
    const int wr = w >> 1, wc = w & 1;
    const int l16 = lane & 15;
    const int lq = lane >> 4;

    f32x4 acc[4][4] = {};

    const int sr = t >> 1;
    const int c16 = (t & 1) * 2;

    for (int k0 = 0; k0 < 512; k0 += 32) {
        const uint4* gA = reinterpret_cast<const uint4*>(A + (size_t)(brow + sr) * 512 + k0 + c16 * 8);
        const uint4* gB = reinterpret_cast<const uint4*>(W + (size_t)(bcol + sr) * 512 + k0 + c16 * 8);
        uint4 a0 = gA[0], a1 = gA[1];
        uint4 b0 = gB[0], b1 = gB[1];
        __syncthreads();
        ldsA[(sr * 4 + c16) ^ (sr & 7)]     = a0;
        ldsA[(sr * 4 + c16 + 1) ^ (sr & 7)] = a1;
        ldsB[(sr * 4 + c16) ^ (sr & 7)]     = b0;
        ldsB[(sr * 4 + c16 + 1) ^ (sr & 7)] = b1;
        __syncthreads();
        short8 af[4], bfr[4];
#pragma unroll
        for (int m = 0; m < 4; ++m) {
            int ra = wr * 64 + m * 16 + l16;
            af[m] = *reinterpret_cast<short8*>(&ldsA[(ra * 4 + lq) ^ (ra & 7)]);
            int rb = wc * 64 + m * 16 + l16;
            bfr[m] = *reinterpret_cast<short8*>(&ldsB[(rb * 4 + lq) ^ (rb & 7)]);
        }
#pragma unroll
        for (int m = 0; m < 4; ++m)
#pragma unroll
            for (int n = 0; n < 4; ++n)
                acc[m][n] = __builtin_amdgcn_mfma_f32_16x16x32_bf16(af[m], bfr[n], acc[m][n], 0, 0, 0);
    }

#pragma unroll
    for (int m = 0; m < 4; ++m) {
        int row = brow + wr * 64 + m * 16 + lq * 4;
#pragma unroll
        for (int n = 0; n < 4; ++n) {
            int col = bcol + wc * 64 + n * 16 + l16;
            float bv = bias[col];
            if (OUT_MODE == 2) {
                // V transposed per head: 4 consecutive tokens -> 8B store
                int bh = ((row >> 12) << 3) + (col >> 6);
                int d = col & 63;
                int ntok = row & 4095;
                ushort4 o;
                o.x = f2bf(acc[m][n][0] + bv);
                o.y = f2bf(acc[m][n][1] + bv);
                o.z = f2bf(acc[m][n][2] + bv);
                o.w = f2bf(acc[m][n][3] + bv);
                *reinterpret_cast<ushort4*>(
                    (unsigned short*)Cout + ((size_t)bh * 64 + d) * 4096 + ntok) = o;
            } else {
#pragma unroll
                for (int r = 0; r < 4; ++r) {
                    float v = (acc[m][n][r] + bv) * scale;
                    if (OUT_MODE == 1) {
                        ((unsigned short*)Cout)[(size_t)(row + r) * 512 + col] = f2bf(v);
                    } else {
                        ((float*)Cout)[(size_t)(row + r) * 512 + col] = v;
                    }
                }
            }
        }
    }
}

// Fused Q/K/V projection: blockIdx.z selects output. V is written transposed.
__global__ __launch_bounds__(256)
void gemm_qkv(const unsigned short* __restrict__ xb,
              const unsigned short* __restrict__ Wall,   // Wq|Wk|Wv packed
              const float* __restrict__ bq, const float* __restrict__ bk,
              const float* __restrict__ bv,
              unsigned short* __restrict__ Qb, unsigned short* __restrict__ Kb,
              unsigned short* __restrict__ Vt, float cl) {
    __shared__ uint4 ldsA[128 * 4];
    __shared__ uint4 ldsB[128 * 4];
    int z = blockIdx.z;
    const unsigned short* W = Wall + (size_t)z * DD * DD;
    int brow = (int)blockIdx.y * 128, bcol = (int)blockIdx.x * 128;
    if (z == 0) {
        gemm_tile<1>(xb, W, bq, Qb, cl, brow, bcol, ldsA, ldsB);
    } else if (z == 1) {
        gemm_tile<1>(xb, W, bk, Kb, 1.0f, brow, bcol, ldsA, ldsB);
    } else {
        gemm_tile<2>(xb, W, bv, Vt, 1.0f, brow, bcol, ldsA, ldsB);
    }
}

// Output projection (f32 out)
__global__ __launch_bounds__(256)
void gemm_bias_f32(const unsigned short* __restrict__ A,
                   const unsigned short* __restrict__ W,
                   const float* __restrict__ bias,
                   float* __restrict__ Cout) {
    __shared__ uint4 ldsA[128 * 4];
    __shared__ uint4 ldsB[128 * 4];
    gemm_tile<0>(A, W, bias, Cout, 1.0f,
                 (int)blockIdx.y * 128, (int)blockIdx.x * 128, ldsA, ldsB);
}

// ---------------- Flash attention -------------------------------------------
// R15: 2-wave blocks (64 q-rows), 2048 blocks. Barrier group = 2 waves; the
// other waves resident on each SIMD belong to INDEPENDENT blocks -> stall
// decorrelation. Per-wave body/swizzles/skeleton identical to R12 (best:
// 209us, VGPR 84, no spill). Each wave stages 8 x 1KB (vmcnt(8)).
__global__ __launch_bounds__(128)
void flash_attn(const unsigned short* __restrict__ Qb,
                const unsigned short* __restrict__ Kb,
                const unsigned short* __restrict__ Vt,
                unsigned short* __restrict__ Ob) {
    __shared__ __align__(16) char lds[32768];  // 2 x (K 8KB + V 8KB)
    const int t = threadIdx.x;
    const int lane = t & 63;
    const int w = t >> 6;                      // 0..1
    // XCD-bijective swizzle: 2048 blocks -> XCD x gets ids [x*256, x*256+256)
    const int nid = (blockIdx.x & 7) * 256 + (blockIdx.x >> 3);
    const int bh = nid >> 6;          // 0..31
    const int qb = nid & 63;          // 0..63
    const int b = bh >> 3, h = bh & 7;
    const int q0 = qb * 64 + w * 32;
    const int l32 = lane & 31;
    const int hi = lane >> 5;

    // staging lane constants
    const int i8 = lane >> 3, g8 = lane & 7;

    // Q fragments (B-operand): col=q=l32, d = c*16 + hi*8 + j
    const unsigned short* qptr = Qb + (size_t)(b * NN + q0 + l32) * DD + h * HD + hi * 8;
    short8 qf[4];
#pragma unroll
    for (int c = 0; c < 4; ++c)
        qf[c] = *reinterpret_cast<const short8*>(qptr + c * 16);

    const f32x16 Z = {};
    f32x16 OT0 = {}, OT1 = {};
    float lsum = 0.f;

    // Precomputed LDS frag byte-offsets (two-axis XOR swizzle)
    int koff[8], voff[8];
#pragma unroll
    for (int sub = 0; sub < 2; ++sub) {
#pragma unroll
        for (int c = 0; c < 4; ++c) {
            int row = sub * 32 + l32;
            int g = (hi + 2 * c) ^ (row & 7) ^ ((row >> 3) & 7);
            koff[sub * 4 + c] = row * 128 + g * 16;
        }
#pragma unroll
        for (int dblk = 0; dblk < 2; ++dblk)
#pragma unroll
            for (int c2 = 0; c2 < 2; ++c2) {
                int row = dblk * 32 + l32;
                int g = ((sub << 2) + (c2 << 1) + hi) ^ (row & 7) ^ ((row >> 3) & 7);
                voff[sub * 4 + dblk * 2 + c2] = 8192 + row * 128 + g * 16;
            }
    }

    // Staging: wave w covers rows [w*32, w*32+32) of the 64-row tile,
    // 4 K-instrs + 4 V-instrs (1KB each). Row = w*32 + jj*8 + i8:
    // row&7 = i8, (row>>3)&7 = (w*4+jj)&7 -> source granule matches
    // the read-side two-axis swizzle.
    const unsigned short* kp[4];
    const unsigned short* vp[4];
#pragma unroll
    for (int jj = 0; jj < 4; ++jj) {
        int rl = w * 32 + jj * 8 + i8;
        int gk = (g8 ^ i8 ^ ((w * 4 + jj) & 7)) * 8;
        kp[jj] = Kb + (size_t)(b * NN + rl) * DD + h * HD + gk;
        vp[jj] = Vt + ((size_t)bh * HD + rl) * NN + gk;
    }

    auto STAGE = [&](int bb) {
#pragma unroll
        for (int jj = 0; jj < 4; ++jj) {
            __builtin_amdgcn_global_load_lds(
                (const __attribute__((address_space(1))) void*)kp[jj],
                (__attribute__((address_space(3))) void*)(lds + bb + (w * 32 + jj * 8) * 128), 16, 0, 0);
            kp[jj] += 64 * DD;
        }
#pragma unroll
        for (int jj = 0; jj < 4; ++jj) {
            __builtin_amdgcn_global_load_lds(
                (const __attribute__((address_space(1))) void*)vp[jj],
                (__attribute__((address_space(3))) void*)(lds + bb + 8192 + (w * 32 + jj * 8) * 128), 16, 0, 0);
            vp[jj] += 64;
        }
    };

    auto softpack = [&](const f32x16& S, short8& pa, short8& pb) {
        unsigned int wq[8];
#pragma unroll
        for (int j = 0; j < 8; ++j) {
            float p0 = __builtin_exp2f(S[2 * j]);
            float p1 = __builtin_exp2f(S[2 * j + 1]);
            lsum += p0 + p1;
            asm("v_cvt_pk_bf16_f32 %0, %1, %2" : "=v"(wq[j]) : "v"(p0), "v"(p1));
        }
        asm("v_permlane32_swap_b32 %0, %1" : "+v"(wq[0]), "+v"(wq[2]));
        asm("v_permlane32_swap_b32 %0, %1" : "+v"(wq[1]), "+v"(wq[3]));
        asm("v_permlane32_swap_b32 %0, %1" : "+v"(wq[4]), "+v"(wq[6]));
        asm("v_permlane32_swap_b32 %0, %1" : "+v"(wq[5]), "+v"(wq[7]));
        uint4v pu0 = {wq[0], wq[1], wq[2], wq[3]};
        uint4v pu1 = {wq[4], wq[5], wq[6], wq[7]};
        pa = __builtin_bit_cast(short8, pu0);
        pb = __builtin_bit_cast(short8, pu1);
    };

    // Lean single-S compute (R12): minimal live set, strictly serial subs.
    auto COMPUTE = [&](int BO) {
#pragma unroll
        for (int sub = 0; sub < 2; ++sub) {
            short8 kf0 = *reinterpret_cast<const short8*>(lds + BO + koff[sub * 4 + 0]);
            short8 kf1 = *reinterpret_cast<const short8*>(lds + BO + koff[sub * 4 + 1]);
            short8 kf2 = *reinterpret_cast<const short8*>(lds + BO + koff[sub * 4 + 2]);
            short8 kf3 = *reinterpret_cast<const short8*>(lds + BO + koff[sub * 4 + 3]);
            f32x16 S;
            S = __builtin_amdgcn_mfma_f32_32x32x16_bf16(kf0, qf[0], Z, 0, 0, 0);
            S = __builtin_amdgcn_mfma_f32_32x32x16_bf16(kf1, qf[1], S, 0, 0, 0);
            S = __builtin_amdgcn_mfma_f32_32x32x16_bf16(kf2, qf[2], S, 0, 0, 0);
            S = __builtin_amdgcn_mfma_f32_32x32x16_bf16(kf3, qf[3], S, 0, 0, 0);
            // V frags land while softpack runs
            short8 vf0 = *reinterpret_cast<const short8*>(lds + BO + voff[sub * 4 + 0]);
            short8 vf1 = *reinterpret_cast<const short8*>(lds + BO + voff[sub * 4 + 1]);
            short8 vf2 = *reinterpret_cast<const short8*>(lds + BO + voff[sub * 4 + 2]);
            short8 vf3 = *reinterpret_cast<const short8*>(lds + BO + voff[sub * 4 + 3]);
            short8 pa, pb;
            softpack(S, pa, pb);
            OT0 = __builtin_amdgcn_mfma_f32_32x32x16_bf16(vf0, pa, OT0, 0, 0, 0);
            OT0 = __builtin_amdgcn_mfma_f32_32x32x16_bf16(vf1, pb, OT0, 0, 0, 0);
            OT1 = __builtin_amdgcn_mfma_f32_32x32x16_bf16(vf2, pa, OT1, 0, 0, 0);
            OT1 = __builtin_amdgcn_mfma_f32_32x32x16_bf16(vf3, pb, OT1, 0, 0, 0);
        }
    };

    // Prologue: stage tile 0, drain once.
    STAGE(0);
    asm volatile("s_waitcnt vmcnt(0)" ::: "memory");
    __builtin_amdgcn_s_barrier();
    asm volatile("" ::: "memory");

    for (int it = 0; it < 32; ++it) {
        // ---- half 0: stage tile 2it+1 -> buf1, compute tile 2it (buf0) ----
        STAGE(16384);
        asm volatile("s_waitcnt vmcnt(8)" ::: "memory");
        __builtin_amdgcn_s_barrier();
        asm volatile("" ::: "memory");
        COMPUTE(0);
        asm volatile("" ::: "memory");
        __builtin_amdgcn_s_barrier();
        asm volatile("" ::: "memory");
        // ---- half 1: stage tile 2it+2 -> buf0, compute tile 2it+1 ----
        if (it != 31) {
            STAGE(0);
            asm volatile("s_waitcnt vmcnt(8)" ::: "memory");
        } else {
            asm volatile("s_waitcnt vmcnt(0)" ::: "memory");
        }
        __builtin_amdgcn_s_barrier();
        asm volatile("" ::: "memory");
        COMPUTE(16384);
        if (it != 31) {
            asm volatile("" ::: "memory");
            __builtin_amdgcn_s_barrier();
            asm volatile("" ::: "memory");
        }
    }

    // --- epilogue: normalize, transpose via LDS (wave-private 4KB in buf0;
    // last reads hit buf1 [16K,32K) -> disjoint, no barrier needed) ---
    lsum += __shfl_xor(lsum, 32);
    float inv = 1.0f / lsum;
    char* lw = lds + w * 4096;
#pragma unroll
    for (int dblk = 0; dblk < 2; ++dblk) {
#pragma unroll
        for (int g = 0; g < 4; ++g) {
#pragma unroll
            for (int j = 0; j < 2; ++j) {
                int r = 4 * g + 2 * j;
                int d = dblk * 32 + 8 * g + 2 * j + 4 * hi;
                float a = (dblk ? OT1[r] : OT0[r]) * inv;
                float bqv = (dblk ? OT1[r + 1] : OT0[r + 1]) * inv;
                unsigned int wv;
                asm("v_cvt_pk_bf16_f32 %0, %1, %2" : "=v"(wv) : "v"(a), "v"(bqv));
                int addr = (l32 * 128 + d * 2) ^ ((l32 & 7) << 4);
                *reinterpret_cast<unsigned int*>(lw + addr) = wv;
            }
        }
    }
#pragma unroll
    for (int it = 0; it < 4; ++it) {
        int q = lane >> 1;
        int seg = (lane & 1) + it * 2;
        uint4 val = *reinterpret_cast<uint4*>(lw + ((q * 128 + seg * 16) ^ ((q & 7) << 4)));
        *reinterpret_cast<uint4*>(Ob + (size_t)(b * NN + q0 + q) * DD + h * HD + seg * 8) = val;
    }
}

// ---------------- launch ----------------
extern "C" void kernel_launch(void* const* d_in, const int* in_sizes, int n_in,
                              void* d_out, int out_size, void* d_ws, size_t ws_size,
                              hipStream_t stream) {
    (void)in_sizes; (void)n_in; (void)out_size; (void)ws_size;
    const float* x  = (const float*)d_in[0];
    const float* Wq = (const float*)d_in[1];
    const float* bq = (const float*)d_in[2];
    const float* Wk = (const float*)d_in[3];
    const float* bk = (const float*)d_in[4];
    const float* Wv = (const float*)d_in[5];
    const float* bv = (const float*)d_in[6];
    const float* Wo = (const float*)d_in[7];
    const float* bo = (const float*)d_in[8];
    float* out = (float*)d_out;

    char* ws = (char*)d_ws;
    const size_t BUF = 16777216;  // 16 MB (B*N*D bf16)
    unsigned short* xb  = (unsigned short*)(ws);             // x bf16; later Ob
    unsigned short* Qb  = (unsigned short*)(ws + BUF);
    unsigned short* Kb  = (unsigned short*)(ws + 2 * BUF);
    unsigned short* Vt  = (unsigned short*)(ws + 3 * BUF);   // V transposed (from GEMM)
    unsigned short* Wqb = (unsigned short*)(ws + 4 * BUF);   // Wq|Wk|Wv|Wo packed
    unsigned short* Wob = Wqb + 3 * 262144;
    unsigned short* Ob  = xb;   // alias: x dead after projections

    const int NTOK = BB * NN;  // 16384
    const float cl = 0.125f * 1.4426950408889634f;

    convert_bf16<<<2048, 256, 0, stream>>>(x, xb, NTOK * DD);
    convert_weights<<<512, 256, 0, stream>>>(Wq, Wk, Wv, Wo, Wqb);

    dim3 ggrid(4, NTOK / 128, 3);
    gemm_qkv<<<ggrid, 256, 0, stream>>>(xb, Wqb, bq, bk, bv, Qb, Kb, Vt, cl);

    flash_attn<<<2048, 128, 0, stream>>>(Qb, Kb, Vt, Ob);

    gemm_bias_f32<<<dim3(4, NTOK / 128), 256, 0, stream>>>(Ob, Wob, bo, out);
}

// Round 17
// 269.610 us; speedup vs baseline: 1.1942x; 1.1942x over previous
//
#include <hip/hip_runtime.h>
#include <hip/hip_bf16.h>

// Problem constants
#define BB 4
#define NN 4096
#define DD 512
#define HH 8
#define HD 64

typedef __attribute__((ext_vector_type(4))) float f32x4;
typedef __attribute__((ext_vector_type(16))) float f32x16;
typedef __attribute__((ext_vector_type(8))) short short8;
typedef __attribute__((ext_vector_type(4))) unsigned int uint4v;

static __device__ __forceinline__ unsigned short f2bf(float f) {
    unsigned int u = __float_as_uint(f);
    u += 0x7fff + ((u >> 16) & 1);   // RNE
    return (unsigned short)(u >> 16);
}

// ---------------- f32 -> bf16 conversion ----------------
__global__ void convert_bf16(const float* __restrict__ in,
                             unsigned short* __restrict__ out, int n) {
    int i = (blockIdx.x * blockDim.x + threadIdx.x) * 8;
    int stride = gridDim.x * blockDim.x * 8;
    for (; i + 7 < n; i += stride) {
        f32x4 a = *reinterpret_cast<const f32x4*>(in + i);
        f32x4 b = *reinterpret_cast<const f32x4*>(in + i + 4);
        short8 o;
        o[0] = (short)f2bf(a[0]); o[1] = (short)f2bf(a[1]);
        o[2] = (short)f2bf(a[2]); o[3] = (short)f2bf(a[3]);
        o[4] = (short)f2bf(b[0]); o[5] = (short)f2bf(b[1]);
        o[6] = (short)f2bf(b[2]); o[7] = (short)f2bf(b[3]);
        *reinterpret_cast<short8*>(out + i) = o;
    }
}

// Fused convert of the 4 weight matrices (each 512x512)
__global__ void convert_weights(const float* __restrict__ W0, const float* __restrict__ W1,
                                const float* __restrict__ W2, const float* __restrict__ W3,
                                unsigned short* __restrict__ out) {
    int which = blockIdx.x >> 7;            // 128 blocks per matrix
    const float* src = which == 0 ? W0 : which == 1 ? W1 : which == 2 ? W2 : W3;
    unsigned short* dst = out + (size_t)which * DD * DD;
    int i = ((blockIdx.x & 127) * blockDim.x + threadIdx.x) * 8;
    f32x4 a = *reinterpret_cast<const f32x4*>(src + i);
    f32x4 b = *reinterpret_cast<const f32x4*>(src + i + 4);
    short8 o;
    o[0] = (short)f2bf(a[0]); o[1] = (short)f2bf(a[1]);
    o[2] = (short)f2bf(a[2]); o[3] = (short)f2bf(a[3]);
    o[4] = (short)f2bf(b[0]); o[5] = (short)f2bf(b[1]);
    o[6] = (short)f2bf(b[2]); o[7] = (short)f2bf(b[3]);
    *reinterpret_cast<short8*>(dst + i) = o;
}

// ---------------- GEMM tile body ---------------------------------------------
// OUT_MODE: 0 = f32 row-major, 1 = bf16 row-major, 2 = bf16 V-transposed
// (write Vt[(b*8+h)*64 + d][token], token fastest -> 8B/lane stores)
template <int OUT_MODE>
__device__ __forceinline__
void gemm_tile(const unsigned short* __restrict__ A,
               const unsigned short* __restrict__ W,
               const float* __restrict__ bias,
               void* __restrict__ Cout, float scale,
               int brow, int bcol, uint4* ldsA, uint4* ldsB) {
    const int t = threadIdx.x;
    const int lane = t & 63;
    const int w = t >> 6;
    const int wr = w >> 1, wc = w & 1;
    const int l16 = lane & 15;
    const int lq = lane >> 4;

    f32x4 acc[4][4] = {};

    const int sr = t >> 1;
    const int c16 = (t & 1) * 2;

    for (int k0 = 0; k0 < 512; k0 += 32) {
        const uint4* gA = reinterpret_cast<const uint4*>(A + (size_t)(brow + sr) * 512 + k0 + c16 * 8);
        const uint4* gB = reinterpret_cast<const uint4*>(W + (size_t)(bcol + sr) * 512 + k0 + c16 * 8);
        uint4 a0 = gA[0], a1 = gA[1];
        uint4 b0 = gB[0], b1 = gB[1];
        __syncthreads();
        ldsA[(sr * 4 + c16) ^ (sr & 7)]     = a0;
        ldsA[(sr * 4 + c16 + 1) ^ (sr & 7)] = a1;
        ldsB[(sr * 4 + c16) ^ (sr & 7)]     = b0;
        ldsB[(sr * 4 + c16 + 1) ^ (sr & 7)] = b1;
        __syncthreads();
        short8 af[4], bfr[4];
#pragma unroll
        for (int m = 0; m < 4; ++m) {
            int ra = wr * 64 + m * 16 + l16;
            af[m] = *reinterpret_cast<short8*>(&ldsA[(ra * 4 + lq) ^ (ra & 7)]);
            int rb = wc * 64 + m * 16 + l16;
            bfr[m] = *reinterpret_cast<short8*>(&ldsB[(rb * 4 + lq) ^ (rb & 7)]);
        }
#pragma unroll
        for (int m = 0; m < 4; ++m)
#pragma unroll
            for (int n = 0; n < 4; ++n)
                acc[m][n] = __builtin_amdgcn_mfma_f32_16x16x32_bf16(af[m], bfr[n], acc[m][n], 0, 0, 0);
    }

#pragma unroll
    for (int m = 0; m < 4; ++m) {
        int row = brow + wr * 64 + m * 16 + lq * 4;
#pragma unroll
        for (int n = 0; n < 4; ++n) {
            int col = bcol + wc * 64 + n * 16 + l16;
            float bv = bias[col];
            if (OUT_MODE == 2) {
                // V transposed per head: 4 consecutive tokens -> 8B store
                int bh = ((row >> 12) << 3) + (col >> 6);
                int d = col & 63;
                int ntok = row & 4095;
                ushort4 o;
                o.x = f2bf(acc[m][n][0] + bv);
                o.y = f2bf(acc[m][n][1] + bv);
                o.z = f2bf(acc[m][n][2] + bv);
                o.w = f2bf(acc[m][n][3] + bv);
                *reinterpret_cast<ushort4*>(
                    (unsigned short*)Cout + ((size_t)bh * 64 + d) * 4096 + ntok) = o;
            } else {
#pragma unroll
                for (int r = 0; r < 4; ++r) {
                    float v = (acc[m][n][r] + bv) * scale;
                    if (OUT_MODE == 1) {
                        ((unsigned short*)Cout)[(size_t)(row + r) * 512 + col] = f2bf(v);
                    } else {
                        ((float*)Cout)[(size_t)(row + r) * 512 + col] = v;
                    }
                }
            }
        }
    }
}

// Fused Q/K/V projection: blockIdx.z selects output. V is written transposed.
__global__ __launch_bounds__(256)
void gemm_qkv(const unsigned short* __restrict__ xb,
              const unsigned short* __restrict__ Wall,   // Wq|Wk|Wv packed
              const float* __restrict__ bq, const float* __restrict__ bk,
              const float* __restrict__ bv,
              unsigned short* __restrict__ Qb, unsigned short* __restrict__ Kb,
              unsigned short* __restrict__ Vt, float cl) {
    __shared__ uint4 ldsA[128 * 4];
    __shared__ uint4 ldsB[128 * 4];
    int z = blockIdx.z;
    const unsigned short* W = Wall + (size_t)z * DD * DD;
    int brow = (int)blockIdx.y * 128, bcol = (int)blockIdx.x * 128;
    if (z == 0) {
        gemm_tile<1>(xb, W, bq, Qb, cl, brow, bcol, ldsA, ldsB);
    } else if (z == 1) {
        gemm_tile<1>(xb, W, bk, Kb, 1.0f, brow, bcol, ldsA, ldsB);
    } else {
        gemm_tile<2>(xb, W, bv, Vt, 1.0f, brow, bcol, ldsA, ldsB);
    }
}

// Output projection (f32 out)
__global__ __launch_bounds__(256)
void gemm_bias_f32(const unsigned short* __restrict__ A,
                   const unsigned short* __restrict__ W,
                   const float* __restrict__ bias,
                   float* __restrict__ Cout) {
    __shared__ uint4 ldsA[128 * 4];
    __shared__ uint4 ldsB[128 * 4];
    gemm_tile<0>(A, W, bias, Cout, 1.0f,
                 (int)blockIdx.y * 128, (int)blockIdx.x * 128, ldsA, ldsB);
}

// ---------------- Flash attention -------------------------------------------
// R17 = R12 verbatim (best verified: 208.8us, VGPR 84, no spill, passed).
// 4-wave blocks (128 q-rows); lean single-S COMPUTE under the (256,3) cap;
// double-buffered K/V staging via global_load_lds, counted vmcnt(4),
// 2 barriers per 64-key tile. Q pre-scaled by 1/sqrt(64)*log2(e):
// P = exp2(S), no max-tracking (exact after normalization; S bounded ~9.3).
__global__ __launch_bounds__(256, 3)
void flash_attn(const unsigned short* __restrict__ Qb,
                const unsigned short* __restrict__ Kb,
                const unsigned short* __restrict__ Vt,
                unsigned short* __restrict__ Ob) {
    __shared__ __align__(16) char lds[32768];  // 2 x (K 8KB + V 8KB)
    const int t = threadIdx.x;
    const int lane = t & 63;
    const int w = t >> 6;                      // 0..3
    // XCD-bijective swizzle: 1024 blocks -> XCD x gets ids [x*128, x*128+128)
    const int nid = (blockIdx.x & 7) * 128 + (blockIdx.x >> 3);
    const int bh = nid >> 5;          // 0..31
    const int qb = nid & 31;          // 0..31
    const int b = bh >> 3, h = bh & 7;
    const int q0 = qb * 128 + w * 32;
    const int l32 = lane & 31;
    const int hi = lane >> 5;

    // staging lane constants
    const int i8 = lane >> 3, g8 = lane & 7;

    // Q fragments (B-operand): col=q=l32, d = c*16 + hi*8 + j
    const unsigned short* qptr = Qb + (size_t)(b * NN + q0 + l32) * DD + h * HD + hi * 8;
    short8 qf[4];
#pragma unroll
    for (int c = 0; c < 4; ++c)
        qf[c] = *reinterpret_cast<const short8*>(qptr + c * 16);

    const f32x16 Z = {};
    f32x16 OT0 = {}, OT1 = {};
    float lsum = 0.f;

    // Precomputed LDS frag byte-offsets (two-axis XOR swizzle)
    int koff[8], voff[8];
#pragma unroll
    for (int sub = 0; sub < 2; ++sub) {
#pragma unroll
        for (int c = 0; c < 4; ++c) {
            int row = sub * 32 + l32;
            int g = (hi + 2 * c) ^ (row & 7) ^ ((row >> 3) & 7);
            koff[sub * 4 + c] = row * 128 + g * 16;
        }
#pragma unroll
        for (int dblk = 0; dblk < 2; ++dblk)
#pragma unroll
            for (int c2 = 0; c2 < 2; ++c2) {
                int row = dblk * 32 + l32;
                int g = ((sub << 2) + (c2 << 1) + hi) ^ (row & 7) ^ ((row >> 3) & 7);
                voff[sub * 4 + dblk * 2 + c2] = 8192 + row * 128 + g * 16;
            }
    }

    // Staging: wave w covers rows [w*16, w*16+16) of the 64-row tile.
    const int rowl0 = w * 16 + i8;
    const int rowl1 = w * 16 + 8 + i8;
    const int gs0 = (g8 ^ i8 ^ ((2 * w) & 7)) * 8;
    const int gs1 = (g8 ^ i8 ^ ((2 * w + 1) & 7)) * 8;
    const unsigned short* kp0 = Kb + (size_t)(b * NN + rowl0) * DD + h * HD + gs0;
    const unsigned short* kp1 = Kb + (size_t)(b * NN + rowl1) * DD + h * HD + gs1;
    const unsigned short* vp0 = Vt + ((size_t)bh * HD + rowl0) * NN + gs0;
    const unsigned short* vp1 = Vt + ((size_t)bh * HD + rowl1) * NN + gs1;

    auto STAGE = [&](int bb) {
        __builtin_amdgcn_global_load_lds(
            (const __attribute__((address_space(1))) void*)kp0,
            (__attribute__((address_space(3))) void*)(lds + bb + (w * 16) * 128), 16, 0, 0);
        __builtin_amdgcn_global_load_lds(
            (const __attribute__((address_space(1))) void*)kp1,
            (__attribute__((address_space(3))) void*)(lds + bb + (w * 16 + 8) * 128), 16, 0, 0);
        __builtin_amdgcn_global_load_lds(
            (const __attribute__((address_space(1))) void*)vp0,
            (__attribute__((address_space(3))) void*)(lds + bb + 8192 + (w * 16) * 128), 16, 0, 0);
        __builtin_amdgcn_global_load_lds(
            (const __attribute__((address_space(1))) void*)vp1,
            (__attribute__((address_space(3))) void*)(lds + bb + 8192 + (w * 16 + 8) * 128), 16, 0, 0);
        kp0 += 64 * DD; kp1 += 64 * DD; vp0 += 64; vp1 += 64;
    };

    auto softpack = [&](const f32x16& S, short8& pa, short8& pb) {
        unsigned int wq[8];
#pragma unroll
        for (int j = 0; j < 8; ++j) {
            float p0 = __builtin_exp2f(S[2 * j]);
            float p1 = __builtin_exp2f(S[2 * j + 1]);
            lsum += p0 + p1;
            asm("v_cvt_pk_bf16_f32 %0, %1, %2" : "=v"(wq[j]) : "v"(p0), "v"(p1));
        }
        asm("v_permlane32_swap_b32 %0, %1" : "+v"(wq[0]), "+v"(wq[2]));
        asm("v_permlane32_swap_b32 %0, %1" : "+v"(wq[1]), "+v"(wq[3]));
        asm("v_permlane32_swap_b32 %0, %1" : "+v"(wq[4]), "+v"(wq[6]));
        asm("v_permlane32_swap_b32 %0, %1" : "+v"(wq[5]), "+v"(wq[7]));
        uint4v pu0 = {wq[0], wq[1], wq[2], wq[3]};
        uint4v pu1 = {wq[4], wq[5], wq[6], wq[7]};
        pa = __builtin_bit_cast(short8, pu0);
        pb = __builtin_bit_cast(short8, pu1);
    };

    // Lean single-S compute: minimal live set, strictly serial subs.
    auto COMPUTE = [&](int BO) {
#pragma unroll
        for (int sub = 0; sub < 2; ++sub) {
            short8 kf0 = *reinterpret_cast<const short8*>(lds + BO + koff[sub * 4 + 0]);
            short8 kf1 = *reinterpret_cast<const short8*>(lds + BO + koff[sub * 4 + 1]);
            short8 kf2 = *reinterpret_cast<const short8*>(lds + BO + koff[sub * 4 + 2]);
            short8 kf3 = *reinterpret_cast<const short8*>(lds + BO + koff[sub * 4 + 3]);
            f32x16 S;
            S = __builtin_amdgcn_mfma_f32_32x32x16_bf16(kf0, qf[0], Z, 0, 0, 0);
            S = __builtin_amdgcn_mfma_f32_32x32x16_bf16(kf1, qf[1], S, 0, 0, 0);
            S = __builtin_amdgcn_mfma_f32_32x32x16_bf16(kf2, qf[2], S, 0, 0, 0);
            S = __builtin_amdgcn_mfma_f32_32x32x16_bf16(kf3, qf[3], S, 0, 0, 0);
            // V frags land while softpack runs
            short8 vf0 = *reinterpret_cast<const short8*>(lds + BO + voff[sub * 4 + 0]);
            short8 vf1 = *reinterpret_cast<const short8*>(lds + BO + voff[sub * 4 + 1]);
            short8 vf2 = *reinterpret_cast<const short8*>(lds + BO + voff[sub * 4 + 2]);
            short8 vf3 = *reinterpret_cast<const short8*>(lds + BO + voff[sub * 4 + 3]);
            short8 pa, pb;
            softpack(S, pa, pb);
            OT0 = __builtin_amdgcn_mfma_f32_32x32x16_bf16(vf0, pa, OT0, 0, 0, 0);
            OT0 = __builtin_amdgcn_mfma_f32_32x32x16_bf16(vf1, pb, OT0, 0, 0, 0);
            OT1 = __builtin_amdgcn_mfma_f32_32x32x16_bf16(vf2, pa, OT1, 0, 0, 0);
            OT1 = __builtin_amdgcn_mfma_f32_32x32x16_bf16(vf3, pb, OT1, 0, 0, 0);
        }
    };

    // Prologue: stage tile 0, drain once.
    STAGE(0);
    asm volatile("s_waitcnt vmcnt(0)" ::: "memory");
    __builtin_amdgcn_s_barrier();
    asm volatile("" ::: "memory");

    for (int it = 0; it < 32; ++it) {
        // ---- half 0: stage tile 2it+1 -> buf1, compute tile 2it (buf0) ----
        STAGE(16384);
        asm volatile("s_waitcnt vmcnt(4)" ::: "memory");
        __builtin_amdgcn_s_barrier();
        asm volatile("" ::: "memory");
        COMPUTE(0);
        asm volatile("" ::: "memory");
        __builtin_amdgcn_s_barrier();
        asm volatile("" ::: "memory");
        // ---- half 1: stage tile 2it+2 -> buf0, compute tile 2it+1 ----
        if (it != 31) {
            STAGE(0);
            asm volatile("s_waitcnt vmcnt(4)" ::: "memory");
        } else {
            asm volatile("s_waitcnt vmcnt(0)" ::: "memory");
        }
        __builtin_amdgcn_s_barrier();
        asm volatile("" ::: "memory");
        COMPUTE(16384);
        if (it != 31) {
            asm volatile("" ::: "memory");
            __builtin_amdgcn_s_barrier();
            asm volatile("" ::: "memory");
        }
    }

    // --- epilogue: normalize, transpose via LDS (wave-private 4KB region) ---
    lsum += __shfl_xor(lsum, 32);
    float inv = 1.0f / lsum;
    char* lw = lds + w * 4096;
#pragma unroll
    for (int dblk = 0; dblk < 2; ++dblk) {
#pragma unroll
        for (int g = 0; g < 4; ++g) {
#pragma unroll
            for (int j = 0; j < 2; ++j) {
                int r = 4 * g + 2 * j;
                int d = dblk * 32 + 8 * g + 2 * j + 4 * hi;
                float a = (dblk ? OT1[r] : OT0[r]) * inv;
                float bqv = (dblk ? OT1[r + 1] : OT0[r + 1]) * inv;
                unsigned int wv;
                asm("v_cvt_pk_bf16_f32 %0, %1, %2" : "=v"(wv) : "v"(a), "v"(bqv));
                int addr = (l32 * 128 + d * 2) ^ ((l32 & 7) << 4);
                *reinterpret_cast<unsigned int*>(lw + addr) = wv;
            }
        }
    }
#pragma unroll
    for (int it = 0; it < 4; ++it) {
        int q = lane >> 1;
        int seg = (lane & 1) + it * 2;
        uint4 val = *reinterpret_cast<uint4*>(lw + ((q * 128 + seg * 16) ^ ((q & 7) << 4)));
        *reinterpret_cast<uint4*>(Ob + (size_t)(b * NN + q0 + q) * DD + h * HD + seg * 8) = val;
    }
}

// ---------------- launch ----------------
extern "C" void kernel_launch(void* const* d_in, const int* in_sizes, int n_in,
                              void* d_out, int out_size, void* d_ws, size_t ws_size,
                              hipStream_t stream) {
    (void)in_sizes; (void)n_in; (void)out_size; (void)ws_size;
    const float* x  = (const float*)d_in[0];
    const float* Wq = (const float*)d_in[1];
    const float* bq = (const float*)d_in[2];
    const float* Wk = (const float*)d_in[3];
    const float* bk = (const float*)d_in[4];
    const float* Wv = (const float*)d_in[5];
    const float* bv = (const float*)d_in[6];
    const float* Wo = (const float*)d_in[7];
    const float* bo = (const float*)d_in[8];
    float* out = (float*)d_out;

    char* ws = (char*)d_ws;
    const size_t BUF = 16777216;  // 16 MB (B*N*D bf16)
    unsigned short* xb  = (unsigned short*)(ws);             // x bf16; later Ob
    unsigned short* Qb  = (unsigned short*)(ws + BUF);
    unsigned short* Kb  = (unsigned short*)(ws + 2 * BUF);
    unsigned short* Vt  = (unsigned short*)(ws + 3 * BUF);   // V transposed (from GEMM)
    unsigned short* Wqb = (unsigned short*)(ws + 4 * BUF);   // Wq|Wk|Wv|Wo packed
    unsigned short* Wob = Wqb + 3 * 262144;
    unsigned short* Ob  = xb;   // alias: x dead after projections

    const int NTOK = BB * NN;  // 16384
    const float cl = 0.125f * 1.4426950408889634f;

    convert_bf16<<<2048, 256, 0, stream>>>(x, xb, NTOK * DD);
    convert_weights<<<512, 256, 0, stream>>>(Wq, Wk, Wv, Wo, Wqb);

    dim3 ggrid(4, NTOK / 128, 3);
    gemm_qkv<<<ggrid, 256, 0, stream>>>(xb, Wqb, bq, bk, bv, Qb, Kb, Vt, cl);

    flash_attn<<<1024, 256, 0, stream>>>(Qb, Kb, Vt, Ob);

    gemm_bias_f32<<<dim3(4, NTOK / 128), 256, 0, stream>>>(Ob, Wob, bo, out);
}